// Round 15
// baseline (149.109 us; speedup 1.0000x reference)
//
#include <hip/hip_runtime.h>
#include <hip/hip_bf16.h>
#include <cstdint>

// B=8 N=64 L=256 H=768 E=1536 NH=12 HD=128 HL=1024 C=42 ; rows = B*N = 512

typedef __attribute__((ext_vector_type(8))) short short8_t;
typedef __attribute__((ext_vector_type(4))) float f32x4_t;

__device__ __forceinline__ uint4 pack8(float4 a, float4 b) {
  union { uint4 u; __hip_bfloat16 h[8]; } pk;
  pk.h[0] = __float2bfloat16(a.x); pk.h[1] = __float2bfloat16(a.y);
  pk.h[2] = __float2bfloat16(a.z); pk.h[3] = __float2bfloat16(a.w);
  pk.h[4] = __float2bfloat16(b.x); pk.h[5] = __float2bfloat16(b.y);
  pk.h[6] = __float2bfloat16(b.z); pk.h[7] = __float2bfloat16(b.w);
  return pk.u;
}

// ---------------- prep_all: [0,512) gather (+avg zero for bid<48),
// [512,2240) transpose+cvt of Wkey/Wque/Wval in 64x64 tiles (24x24x3)
__global__ __launch_bounds__(256) void prep_all_kernel(
    const float* __restrict__ hidden, const int* __restrict__ inds,
    const float* __restrict__ Wkey, const float* __restrict__ Wque, const float* __restrict__ Wval,
    float* __restrict__ cat, __hip_bfloat16* __restrict__ cat16,
    __hip_bfloat16* __restrict__ Wt16, float* __restrict__ avg0) {
  const int bid = blockIdx.x, tid = threadIdx.x;
  if (bid < 512) {
    if (bid < 48) avg0[bid * 256 + tid] = 0.f;
    int bn = bid;
    int i0 = inds[bn * 2 + 0], i1 = inds[bn * 2 + 1];
    const float* r0 = hidden + ((size_t)bn * 256 + i0) * 768;
    const float* r1 = hidden + ((size_t)bn * 256 + i1) * 768;
    float* c = cat + (size_t)bn * 1536;
    __hip_bfloat16* c16 = cat16 + (size_t)bn * 1536;
    for (int i = tid; i < 768; i += 256) {
      float a = r0[i], b = r1[i];
      c[i] = a; c[768 + i] = b;
      c16[i] = __float2bfloat16(a); c16[768 + i] = __float2bfloat16(b);
    }
  } else {
    int b2 = bid - 512;
    int z = b2 / 576, rem = b2 % 576, by = rem / 24, bx = rem % 24;
    const float* W = z == 0 ? Wkey : (z == 1 ? Wque : Wval);
    __hip_bfloat16* O = Wt16 + (size_t)z * 1536 * 1536;
    __shared__ float tile[64][65];   // 16.6 KB
    int n0 = bx * 64, k0 = by * 64;
    int r = tid >> 2, q = tid & 3;
#pragma unroll
    for (int j = 0; j < 4; ++j) {
      float4 v = *(const float4*)(W + (size_t)(k0 + r) * 1536 + n0 + q * 16 + j * 4);
      tile[r][q * 16 + j * 4 + 0] = v.x; tile[r][q * 16 + j * 4 + 1] = v.y;
      tile[r][q * 16 + j * 4 + 2] = v.z; tile[r][q * 16 + j * 4 + 3] = v.w;
    }
    __syncthreads();
    union { uint4 u[2]; __hip_bfloat16 h[16]; } pk;
#pragma unroll
    for (int i = 0; i < 16; ++i) pk.h[i] = __float2bfloat16(tile[q * 16 + i][r]);
    __hip_bfloat16* dst = O + (size_t)(n0 + r) * 1536 + k0 + q * 16;
    *(uint4*)dst = pk.u[0];
    *(uint4*)(dst + 8) = pk.u[1];
  }
}

// ---------------- bf16 MFMA GEMM (64x64 tile, BK=64, XOR-swizzled LDS) + XCD remap.
// 1-D grid: blocks [0,576) (or [0,192) for CMODE=2) are GEMM tiles; if PREPW, tail blocks
// (x4-fattened): [576,1600) Whh swizzle+cvt, [1600,2464) in_proj cvt, [2464,2752) out_proj cvt.
// CMODE: 0 = fp32 store, 1 = bf16 store, 2 = fused avg (atomicAdd sum_rows (C+bias)*cat/64)
// BF32B: B source is fp32 [N][K] k-major, converted inline (else prepped bf16 [N][K]).
template <int CMODE, bool BIAS, bool BF32B, bool PREPW>
__global__ __launch_bounds__(256) void mfma_gemm(
    const __hip_bfloat16* __restrict__ A, long As,
    const void* __restrict__ Bmv, long Bs,
    const float* __restrict__ bias, long biasS,
    void* __restrict__ Cp, long Cs,
    const float* __restrict__ catp, float* __restrict__ avgp,
    const float* __restrict__ Whh_f, const float* __restrict__ Whh_b,
    __hip_bfloat16* __restrict__ whh16s,
    const float* __restrict__ ipw, const float* __restrict__ opw,
    __hip_bfloat16* __restrict__ inproj16, __hip_bfloat16* __restrict__ outproj16) {
  constexpr int K = 1536, N = 1536;
  const int bid = blockIdx.x, t = threadIdx.x;
  if (PREPW && bid >= 576) {
    int tb = bid - 576;
    if (tb < 1024) {
#pragma unroll
      for (int c = 0; c < 4; ++c) {
        int id = tb * 1024 + c * 256 + t;              // 0..2^20-1
        int lane = id & 63, half = (id >> 6) & 1, row = (id >> 7) & 4095, d = id >> 19;
        const float* W = d ? Whh_b : Whh_f;
        const float* srcp = W + (size_t)row * 1024 + half * 512 + lane;
        union { uint4 u; __hip_bfloat16 h[8]; } pk;
#pragma unroll
        for (int e = 0; e < 8; ++e) pk.h[e] = __float2bfloat16(srcp[e * 64]);
        *(uint4*)(whh16s + (size_t)id * 8) = pk.u;
      }
    } else {
      const float* src; __hip_bfloat16* dst; int base;
      if (tb < 1888) { src = ipw; dst = inproj16; base = (tb - 1024) * 1024; }
      else { src = opw; dst = outproj16; base = (tb - 1888) * 1024; }
#pragma unroll
      for (int c = 0; c < 4; ++c) {
        int i = base + c * 256 + t;
        float4 a = ((const float4*)src)[2 * i], b = ((const float4*)src)[2 * i + 1];
        *(uint4*)(dst + (size_t)i * 8) = pack8(a, b);
      }
    }
    return;
  }
  const int bx = bid % 24, by = (bid / 24) % 8, z = bid / 192;
  A += (size_t)z * As;
  if (BIAS) bias += (size_t)z * biasS;
  __shared__ __align__(16) short Abuf[64 * 64];
  __shared__ __align__(16) short Bbuf[64 * 64];
  // XCD remap: column bxs constant per XCD group
  const int L = by * 24 + bx;
  const int bxs = (L & 7) + 8 * ((L >> 3) % 3);
  const int bys = (L >> 3) / 3;
  const int i0 = bys * 64, j0 = bxs * 64;
  const int row = t >> 2, kq = t & 3;
  const int lane = t & 63, wave = t >> 6, wr = wave >> 1, wc = wave & 1;
  f32x4_t acc[2][2] = {};

  const char* Ag = (const char*)(A + (size_t)(i0 + row) * K) + kq * 32;
  const char* Bg;
  if (BF32B)
    Bg = (const char*)((const float*)Bmv + (size_t)z * Bs + (size_t)(j0 + row) * K) + kq * 64;
  else
    Bg = (const char*)((const __hip_bfloat16*)Bmv + (size_t)z * Bs + (size_t)(j0 + row) * K) + kq * 32;
  const int swz = (row & 7) << 4;
  char* Asw0 = (char*)Abuf + ((row * 128 + kq * 32) ^ swz);
  char* Asw1 = (char*)Abuf + ((row * 128 + kq * 32 + 16) ^ swz);
  char* Bsw0 = (char*)Bbuf + ((row * 128 + kq * 32) ^ swz);
  char* Bsw1 = (char*)Bbuf + ((row * 128 + kq * 32 + 16) ^ swz);

  for (int kb = 0; kb < K * 2; kb += 128) {
    uint4 a0 = *(const uint4*)(Ag + kb);
    uint4 a1 = *(const uint4*)(Ag + kb + 16);
    uint4 b0, b1;
    if (BF32B) {
      const char* p = Bg + kb * 2;
      float4 f0 = *(const float4*)(p);
      float4 f1 = *(const float4*)(p + 16);
      float4 f2 = *(const float4*)(p + 32);
      float4 f3 = *(const float4*)(p + 48);
      b0 = pack8(f0, f1); b1 = pack8(f2, f3);
    } else {
      b0 = *(const uint4*)(Bg + kb);
      b1 = *(const uint4*)(Bg + kb + 16);
    }
    __syncthreads();
    *(uint4*)Asw0 = a0; *(uint4*)Asw1 = a1;
    *(uint4*)Bsw0 = b0; *(uint4*)Bsw1 = b1;
    __syncthreads();
#pragma unroll
    for (int ks = 0; ks < 2; ++ks) {
      short8_t af[2], bfr[2];
#pragma unroll
      for (int mi = 0; mi < 2; ++mi) {
        int rr = wr * 32 + mi * 16 + (lane & 15);
        int off = (rr * 128 + ks * 64 + (lane >> 4) * 16) ^ ((rr & 7) << 4);
        af[mi] = *(const short8_t*)((const char*)Abuf + off);
      }
#pragma unroll
      for (int ni = 0; ni < 2; ++ni) {
        int rr = wc * 32 + ni * 16 + (lane & 15);
        int off = (rr * 128 + ks * 64 + (lane >> 4) * 16) ^ ((rr & 7) << 4);
        bfr[ni] = *(const short8_t*)((const char*)Bbuf + off);
      }
#pragma unroll
      for (int mi = 0; mi < 2; ++mi)
#pragma unroll
        for (int ni = 0; ni < 2; ++ni)
          acc[mi][ni] = __builtin_amdgcn_mfma_f32_16x16x32_bf16(af[mi], bfr[ni], acc[mi][ni], 0, 0, 0);
    }
  }
  if (CMODE == 2) {
#pragma unroll
    for (int ni = 0; ni < 2; ++ni) {
      int col = j0 + wc * 32 + ni * 16 + (lane & 15);
      float bv = bias[col];
      float p = 0.f;
#pragma unroll
      for (int mi = 0; mi < 2; ++mi) {
        int rbase = i0 + wr * 32 + mi * 16 + (lane >> 4) * 4;
#pragma unroll
        for (int r = 0; r < 4; ++r) {
          float val = acc[mi][ni][r] + bv;
          p += val * catp[(size_t)(rbase + r) * 1536 + col];
        }
      }
      p += __shfl_xor(p, 16);
      p += __shfl_xor(p, 32);
      if (lane < 16) atomicAdd(&avgp[(size_t)bys * 1536 + col], p * (1.0f / 64.0f));
    }
  } else {
#pragma unroll
    for (int mi = 0; mi < 2; ++mi)
#pragma unroll
      for (int ni = 0; ni < 2; ++ni) {
        int r0 = i0 + wr * 32 + mi * 16 + (lane >> 4) * 4;
        int col = j0 + wc * 32 + ni * 16 + (lane & 15);
        float bv = BIAS ? bias[col] : 0.f;
#pragma unroll
        for (int r = 0; r < 4; ++r) {
          float val = acc[mi][ni][r] + bv;
          if (CMODE == 1)
            ((__hip_bfloat16*)Cp)[(size_t)z * Cs + (size_t)(r0 + r) * N + col] = __float2bfloat16(val);
          else
            ((float*)Cp)[(size_t)z * Cs + (size_t)(r0 + r) * N + col] = val;
        }
      }
  }
}

// ---------------- MFMA attention: one block per (b,h); 96 blocks; bf16 in/out.
__global__ __launch_bounds__(256) void attn2_kernel(
    const __hip_bfloat16* __restrict__ qkv, __hip_bfloat16* __restrict__ o) {
  __shared__ __align__(16) ushort Qs[64 * 128];
  __shared__ __align__(16) ushort Ks[64 * 128];
  __shared__ __align__(16) ushort Vt[128 * 72];
  __shared__ __align__(16) ushort Ps[64 * 72];
  __shared__ float redmax[2][64];
  __shared__ float redsum[2][64];
  const int b = blockIdx.x / 12, h = blockIdx.x % 12;
  const int tid = threadIdx.x, lane = tid & 63, wave = tid >> 6;
  const int wr = wave >> 1, wc = wave & 1;
  const size_t base = (size_t)b * 64 * 1536 + (size_t)h * 128;
  const __hip_bfloat16* qg = qkv + base;
  const __hip_bfloat16* kg = qkv + 786432 + base;
  const __hip_bfloat16* vg = qkv + 2 * 786432 + base;

  for (int s = tid; s < 1024; s += 256) {
    int row = s >> 4, q4 = s & 15;
    int q4s = (q4 & 8) | ((q4 & 7) ^ (row & 7));
    uint4 qv = *(const uint4*)(qg + (size_t)row * 1536 + q4 * 8);
    uint4 kv = *(const uint4*)(kg + (size_t)row * 1536 + q4 * 8);
    *(uint4*)&Qs[row * 128 + q4s * 8] = qv;
    *(uint4*)&Ks[row * 128 + q4s * 8] = kv;
    uint4 vv = *(const uint4*)(vg + (size_t)row * 1536 + q4 * 8);
    const ushort* ve = (const ushort*)&vv;
    int colv = (((row >> 3) ^ (q4 & 7)) << 3) | (row & 7);
#pragma unroll
    for (int e = 0; e < 8; ++e) Vt[(q4 * 8 + e) * 72 + colv] = ve[e];
  }
  __syncthreads();

  f32x4_t sacc[2][2] = {};
#pragma unroll
  for (int ks = 0; ks < 4; ++ks) {
    short8_t qf[2], kf[2];
#pragma unroll
    for (int mi = 0; mi < 2; ++mi) {
      int rr = wr * 32 + mi * 16 + (lane & 15);
      int slot = ks * 4 + (lane >> 4);
      int slot2 = (slot & 8) | ((slot & 7) ^ (rr & 7));
      qf[mi] = *(const short8_t*)&Qs[rr * 128 + slot2 * 8];
    }
#pragma unroll
    for (int ni = 0; ni < 2; ++ni) {
      int rr = wc * 32 + ni * 16 + (lane & 15);
      int slot = ks * 4 + (lane >> 4);
      int slot2 = (slot & 8) | ((slot & 7) ^ (rr & 7));
      kf[ni] = *(const short8_t*)&Ks[rr * 128 + slot2 * 8];
    }
#pragma unroll
    for (int mi = 0; mi < 2; ++mi)
#pragma unroll
      for (int ni = 0; ni < 2; ++ni)
        sacc[mi][ni] = __builtin_amdgcn_mfma_f32_16x16x32_bf16(qf[mi], kf[ni], sacc[mi][ni], 0, 0, 0);
  }

  const float scale = 0.08838834764831845f;
  float pv[2][2][4];
#pragma unroll
  for (int mi = 0; mi < 2; ++mi)
#pragma unroll
    for (int r = 0; r < 4; ++r) {
      float a0 = sacc[mi][0][r] * scale, a1 = sacc[mi][1][r] * scale;
      pv[mi][0][r] = a0; pv[mi][1][r] = a1;
      float m0 = fmaxf(a0, a1);
      m0 = fmaxf(m0, __shfl_xor(m0, 1));
      m0 = fmaxf(m0, __shfl_xor(m0, 2));
      m0 = fmaxf(m0, __shfl_xor(m0, 4));
      m0 = fmaxf(m0, __shfl_xor(m0, 8));
      if ((lane & 15) == 0) redmax[wc][wr * 32 + mi * 16 + (lane >> 4) * 4 + r] = m0;
    }
  __syncthreads();
#pragma unroll
  for (int mi = 0; mi < 2; ++mi)
#pragma unroll
    for (int r = 0; r < 4; ++r) {
      int row = wr * 32 + mi * 16 + (lane >> 4) * 4 + r;
      float gm = fmaxf(redmax[0][row], redmax[1][row]);
      float e0 = __expf(pv[mi][0][r] - gm);
      float e1 = __expf(pv[mi][1][r] - gm);
      pv[mi][0][r] = e0; pv[mi][1][r] = e1;
      float s0 = e0 + e1;
      s0 += __shfl_xor(s0, 1);
      s0 += __shfl_xor(s0, 2);
      s0 += __shfl_xor(s0, 4);
      s0 += __shfl_xor(s0, 8);
      if ((lane & 15) == 0) redsum[wc][row] = s0;
      int col0 = wc * 32 + (lane & 15);
      Ps[row * 72 + col0] = __bfloat16_as_ushort(__float2bfloat16(e0));
      Ps[row * 72 + col0 + 16] = __bfloat16_as_ushort(__float2bfloat16(e1));
    }
  __syncthreads();

  f32x4_t oacc[2][4] = {};
#pragma unroll
  for (int ks = 0; ks < 2; ++ks) {
    short8_t pf[2], vf[4];
#pragma unroll
    for (int mi = 0; mi < 2; ++mi) {
      int rr = wr * 32 + mi * 16 + (lane & 15);
      pf[mi] = *(const short8_t*)&Ps[rr * 72 + ks * 32 + (lane >> 4) * 8];
    }
#pragma unroll
    for (int ni = 0; ni < 4; ++ni) {
      int rr = wc * 64 + ni * 16 + (lane & 15);
      int mb = (ks * 4 + (lane >> 4)) ^ ((rr >> 3) & 7);
      vf[ni] = *(const short8_t*)&Vt[rr * 72 + mb * 8];
    }
#pragma unroll
    for (int mi = 0; mi < 2; ++mi)
#pragma unroll
      for (int ni = 0; ni < 4; ++ni)
        oacc[mi][ni] = __builtin_amdgcn_mfma_f32_16x16x32_bf16(pf[mi], vf[ni], oacc[mi][ni], 0, 0, 0);
  }

#pragma unroll
  for (int mi = 0; mi < 2; ++mi)
#pragma unroll
    for (int r = 0; r < 4; ++r) {
      int row = wr * 32 + mi * 16 + (lane >> 4) * 4 + r;
      float inv = 1.f / (redsum[0][row] + redsum[1][row]);
#pragma unroll
      for (int ni = 0; ni < 4; ++ni) {
        int col = wc * 64 + ni * 16 + (lane & 15);
        o[base + (size_t)row * 1536 + col] = __float2bfloat16(oacc[mi][ni][r] * inv);
      }
    }
}

// ---------------- lstm_pre3: 2048 blocks; block bid owns (d = bid>>10, unit u = bid&1023);
// wave w computes gate-row j = w*1024+u for all 8 r. Fuses LSTM step 0 (h=0 -> gates=xg).
__global__ __launch_bounds__(256) void lstm_pre3_kernel(
    const float* __restrict__ avg,
    const float* __restrict__ Wih_f, const float* __restrict__ bih_f, const float* __restrict__ bhh_f,
    const float* __restrict__ Wih_b, const float* __restrict__ bih_b, const float* __restrict__ bhh_b,
    float* __restrict__ xg, float* __restrict__ hstate, float* __restrict__ cstate,
    float* __restrict__ hout) {
  __shared__ float g4[4];
  const int bid = blockIdx.x, tid = threadIdx.x;
  const int wave = tid >> 6, lane = tid & 63;
  const int d = bid >> 10, u = bid & 1023;
  const int j = wave * 1024 + u;
  const float* W = d ? Wih_b : Wih_f;
  const float4* wrow = (const float4*)(W + (size_t)j * 1536);
  float4 w[6];
#pragma unroll
  for (int c = 0; c < 6; ++c) w[c] = wrow[c * 64 + lane];
  float s[8] = {};
#pragma unroll
  for (int r = 0; r < 8; ++r) {
    const float4* av = (const float4*)(avg + (size_t)r * 1536);
#pragma unroll
    for (int c = 0; c < 6; ++c) {
      float4 x = av[c * 64 + lane];
      s[r] += w[c].x * x.x + w[c].y * x.y + w[c].z * x.z + w[c].w * x.w;
    }
  }
#pragma unroll
  for (int r = 0; r < 8; ++r)
#pragma unroll
    for (int off = 32; off; off >>= 1) s[r] += __shfl_xor(s[r], off);
  const int r0 = d ? 7 : 0;
  if (lane == 0) {
    float bias = d ? (bih_b[j] + bhh_b[j]) : (bih_f[j] + bhh_f[j]);
#pragma unroll
    for (int r = 0; r < 8; ++r) xg[((size_t)d * 8 + r) * 4096 + j] = s[r] + bias;
    g4[wave] = s[r0] + bias;
  }
  __syncthreads();
  if (tid == 0) {
    float iv = 1.f / (1.f + __expf(-g4[0]));
    float ov = 1.f / (1.f + __expf(-g4[3]));
    float cn = iv * tanhf(g4[2]);
    float hn = ov * tanhf(cn);
    cstate[(size_t)d * 1024 + u] = cn;
    hstate[(size_t)(2 + d) * 1024 + u] = hn;     // read by step s=1 ((s&1)*2+d)
    hout[((size_t)d * 8 + r0) * 1024 + u] = hn;
  }
}

// ---------------- lstm_step2: 512 blocks; block owns dir d=bid>>8, units u0=(bid&255)*4.
__global__ __launch_bounds__(256) void lstm_step2_kernel(
    const __hip_bfloat16* __restrict__ whh16s, const float* __restrict__ xg,
    float* __restrict__ hstate, float* __restrict__ cstate,
    float* __restrict__ hout, int s) {
  const int bid = blockIdx.x;
  const int d = bid >> 8, u0 = (bid & 255) * 4;
  const int tid = threadIdx.x, wave = tid >> 6, lane = tid & 63;
  const float* hread = hstate + ((size_t)(s & 1) * 2 + d) * 1024;
  float* hwrite = hstate + ((size_t)((s + 1) & 1) * 2 + d) * 1024;
  float* c = cstate + (size_t)d * 1024;
  const int r = d ? (7 - s) : s;

  float hreg[16];
#pragma unroll
  for (int cc = 0; cc < 16; ++cc) hreg[cc] = hread[cc * 64 + lane];

  __shared__ float gsm[4][4];
#pragma unroll
  for (int ui = 0; ui < 4; ++ui) {
    int row = wave * 1024 + u0 + ui;
    const uint4* wp = (const uint4*)whh16s + ((size_t)d * 4096 + row) * 128 + lane;
    uint4 w0 = wp[0];
    uint4 w1 = wp[64];
    float sacc = 0.f;
#pragma unroll
    for (int e4 = 0; e4 < 4; ++e4) {
      uint32_t u = ((const uint32_t*)&w0)[e4];
      sacc += __uint_as_float(u << 16) * hreg[2 * e4] +
              __uint_as_float(u & 0xffff0000u) * hreg[2 * e4 + 1];
    }
#pragma unroll
    for (int e4 = 0; e4 < 4; ++e4) {
      uint32_t u = ((const uint32_t*)&w1)[e4];
      sacc += __uint_as_float(u << 16) * hreg[8 + 2 * e4] +
              __uint_as_float(u & 0xffff0000u) * hreg[8 + 2 * e4 + 1];
    }
#pragma unroll
    for (int off = 32; off; off >>= 1) sacc += __shfl_xor(sacc, off);
    if (lane == 0) gsm[wave][ui] = sacc;
  }
  __syncthreads();
  if (tid < 4) {
    int u = u0 + tid;
    const float* xgr = xg + ((size_t)d * 8 + r) * 4096;
    float gi = gsm[0][tid] + xgr[u];
    float gf = gsm[1][tid] + xgr[1024 + u];
    float gg = gsm[2][tid] + xgr[2048 + u];
    float go = gsm[3][tid] + xgr[3072 + u];
    float iv = 1.f / (1.f + __expf(-gi));
    float fv = 1.f / (1.f + __expf(-gf));
    float ov = 1.f / (1.f + __expf(-go));
    float cold = c[u];
    float cn = fv * cold + iv * tanhf(gg);
    float hn = ov * tanhf(cn);
    c[u] = cn;
    hwrite[u] = hn;
    hout[((size_t)d * 8 + r) * 1024 + u] = hn;
  }
}

// ---------------- logits = lstm_out @ out_w.T + out_b ; softmax over 42 classes
__global__ __launch_bounds__(256) void final_kernel(
    const float* __restrict__ hout, const float* __restrict__ out_w,
    const float* __restrict__ out_b, float* __restrict__ outp) {
  __shared__ float lo[2048];
  __shared__ float logits[64];
  const int s = blockIdx.x, tid = threadIdx.x;
  for (int i = tid; i < 1024; i += 256) {
    lo[i] = hout[(size_t)s * 1024 + i];
    lo[1024 + i] = hout[(size_t)(8 + s) * 1024 + i];
  }
  __syncthreads();
  const int wave = tid >> 6, lane = tid & 63;
  for (int cls = wave; cls < 42; cls += 4) {
    const float4* wr = (const float4*)(out_w + (size_t)cls * 2048);
    const float4* xr = (const float4*)lo;
    float acc = 0.f;
#pragma unroll
    for (int t = 0; t < 8; ++t) {
      int k4 = lane + t * 64;
      float4 w = wr[k4];
      float4 x = xr[k4];
      acc += w.x * x.x + w.y * x.y + w.z * x.z + w.w * x.w;
    }
#pragma unroll
    for (int off = 32; off; off >>= 1) acc += __shfl_xor(acc, off);
    if (lane == 0) logits[cls] = acc + out_b[cls];
  }
  __syncthreads();
  if (tid == 0) {
    float mx = -1e30f;
    for (int c2 = 0; c2 < 42; ++c2) mx = fmaxf(mx, logits[c2]);
    float sum = 0.f;
    for (int c2 = 0; c2 < 42; ++c2) {
      float e = __expf(logits[c2] - mx);
      logits[c2] = e;
      sum += e;
    }
    float inv = 1.f / sum;
    for (int c2 = 0; c2 < 42; ++c2) outp[s * 42 + c2] = logits[c2] * inv;
  }
}

extern "C" void kernel_launch(void* const* d_in, const int* in_sizes, int n_in,
                              void* d_out, int out_size, void* d_ws, size_t ws_size,
                              hipStream_t stream) {
  const float* hidden     = (const float*)d_in[0];
  const int*   inds       = (const int*)d_in[1];
  const float* Wkey       = (const float*)d_in[2];
  const float* Wque       = (const float*)d_in[3];
  const float* Wval       = (const float*)d_in[4];
  const float* in_proj_w  = (const float*)d_in[5];
  const float* in_proj_b  = (const float*)d_in[6];
  const float* out_proj_w = (const float*)d_in[7];
  const float* out_proj_b = (const float*)d_in[8];
  const float* Wih_f      = (const float*)d_in[9];
  const float* Whh_f      = (const float*)d_in[10];
  const float* bih_f      = (const float*)d_in[11];
  const float* bhh_f      = (const float*)d_in[12];
  const float* Wih_b      = (const float*)d_in[13];
  const float* Whh_b      = (const float*)d_in[14];
  const float* bih_b      = (const float*)d_in[15];
  const float* bhh_b      = (const float*)d_in[16];
  const float* out_w      = (const float*)d_in[17];
  const float* out_b      = (const float*)d_in[18];
  float* out = (float*)d_out;

  float* ws = (float*)d_ws;
  float* cat      = ws;                    // 786432
  float* avg      = cat + 786432;          // 12288
  float* xg       = avg + 12288;           // 65536
  float* hstate   = xg + 65536;            // 4096
  float* cstate   = hstate + 4096;         // 2048
  float* hout     = cstate + 2048;         // 16384
  __hip_bfloat16* b16 = (__hip_bfloat16*)(hout + 16384);
  __hip_bfloat16* cat16     = b16;                  // 786432
  __hip_bfloat16* Wt16      = cat16 + 786432;       // 3*1536*1536
  __hip_bfloat16* inproj16  = Wt16 + 7077888;       // 4608*1536
  __hip_bfloat16* outproj16 = inproj16 + 7077888;   // 1536*1536
  __hip_bfloat16* kqv1      = outproj16 + 2359296;  // 3*786432
  __hip_bfloat16* qkv16     = kqv1 + 2359296;       // 3*786432
  __hip_bfloat16* ob16      = qkv16 + 2359296;      // 786432
  __hip_bfloat16* whh16s    = ob16 + 786432;        // 2*4096*1024

  prep_all_kernel<<<2240, 256, 0, stream>>>(hidden, inds, Wkey, Wque, Wval,
                                            cat, cat16, Wt16, avg);

  // stage 1: kqv1[z] = cat @ W_z (bf16 out, B = prepped bf16 Wt16)
  //          + fattened tails: Whh [576,1600), in_proj [1600,2464), out_proj [2464,2752)
  mfma_gemm<1, false, false, true><<<2752, 256, 0, stream>>>(
      cat16, 0, Wt16, 1536L * 1536, nullptr, 0, kqv1, 786432, nullptr, nullptr,
      Whh_f, Whh_b, whh16s, in_proj_w, out_proj_w, inproj16, outproj16);
  // stage 2: qkv16[z] = kqv1[z] @ in_proj_z^T + b_z (bf16 out, prepped bf16 B)
  mfma_gemm<1, true, false, false><<<576, 256, 0, stream>>>(
      kqv1, 786432, inproj16, 1536L * 1536, in_proj_b, 1536, qkv16, 786432,
      nullptr, nullptr, nullptr, nullptr, nullptr, nullptr, nullptr, nullptr, nullptr);

  attn2_kernel<<<96, 256, 0, stream>>>(qkv16, ob16);

  // out_proj fused with avg: avg[b] += sum_n (ob@out_proj^T + b) * cat / 64 (prepped bf16 B)
  mfma_gemm<2, true, false, false><<<192, 256, 0, stream>>>(
      ob16, 0, outproj16, 0, out_proj_b, 0, nullptr, 0, cat, avg,
      nullptr, nullptr, nullptr, nullptr, nullptr, nullptr, nullptr);

  lstm_pre3_kernel<<<2048, 256, 0, stream>>>(avg, Wih_f, bih_f, bhh_f, Wih_b, bih_b, bhh_b,
                                             xg, hstate, cstate, hout);

  for (int s = 1; s < 8; ++s)
    lstm_step2_kernel<<<512, 256, 0, stream>>>(whh16s, xg, hstate, cstate, hout, s);

  final_kernel<<<8, 256, 0, stream>>>(hout, out_w, out_b, out);
}

// Round 16
// 147.535 us; speedup vs baseline: 1.0107x; 1.0107x over previous
//
#include <hip/hip_runtime.h>
#include <hip/hip_bf16.h>
#include <cstdint>

// B=8 N=64 L=256 H=768 E=1536 NH=12 HD=128 HL=1024 C=42 ; rows = B*N = 512

typedef __attribute__((ext_vector_type(8))) short short8_t;
typedef __attribute__((ext_vector_type(4))) float f32x4_t;

__device__ __forceinline__ uint4 pack8(float4 a, float4 b) {
  union { uint4 u; __hip_bfloat16 h[8]; } pk;
  pk.h[0] = __float2bfloat16(a.x); pk.h[1] = __float2bfloat16(a.y);
  pk.h[2] = __float2bfloat16(a.z); pk.h[3] = __float2bfloat16(a.w);
  pk.h[4] = __float2bfloat16(b.x); pk.h[5] = __float2bfloat16(b.y);
  pk.h[6] = __float2bfloat16(b.z); pk.h[7] = __float2bfloat16(b.w);
  return pk.u;
}

// ---------------- prep_all: [0,512) gather (+avg zero for bid<48),
// [512,2240) transpose+cvt of Wkey/Wque/Wval in 64x64 tiles (24x24x3)
__global__ __launch_bounds__(256) void prep_all_kernel(
    const float* __restrict__ hidden, const int* __restrict__ inds,
    const float* __restrict__ Wkey, const float* __restrict__ Wque, const float* __restrict__ Wval,
    float* __restrict__ cat, __hip_bfloat16* __restrict__ cat16,
    __hip_bfloat16* __restrict__ Wt16, float* __restrict__ avg0) {
  const int bid = blockIdx.x, tid = threadIdx.x;
  if (bid < 512) {
    if (bid < 48) avg0[bid * 256 + tid] = 0.f;
    int bn = bid;
    int i0 = inds[bn * 2 + 0], i1 = inds[bn * 2 + 1];
    const float* r0 = hidden + ((size_t)bn * 256 + i0) * 768;
    const float* r1 = hidden + ((size_t)bn * 256 + i1) * 768;
    float* c = cat + (size_t)bn * 1536;
    __hip_bfloat16* c16 = cat16 + (size_t)bn * 1536;
    for (int i = tid; i < 768; i += 256) {
      float a = r0[i], b = r1[i];
      c[i] = a; c[768 + i] = b;
      c16[i] = __float2bfloat16(a); c16[768 + i] = __float2bfloat16(b);
    }
  } else {
    int b2 = bid - 512;
    int z = b2 / 576, rem = b2 % 576, by = rem / 24, bx = rem % 24;
    const float* W = z == 0 ? Wkey : (z == 1 ? Wque : Wval);
    __hip_bfloat16* O = Wt16 + (size_t)z * 1536 * 1536;
    __shared__ float tile[64][65];   // 16.6 KB
    int n0 = bx * 64, k0 = by * 64;
    int r = tid >> 2, q = tid & 3;
#pragma unroll
    for (int j = 0; j < 4; ++j) {
      float4 v = *(const float4*)(W + (size_t)(k0 + r) * 1536 + n0 + q * 16 + j * 4);
      tile[r][q * 16 + j * 4 + 0] = v.x; tile[r][q * 16 + j * 4 + 1] = v.y;
      tile[r][q * 16 + j * 4 + 2] = v.z; tile[r][q * 16 + j * 4 + 3] = v.w;
    }
    __syncthreads();
    union { uint4 u[2]; __hip_bfloat16 h[16]; } pk;
#pragma unroll
    for (int i = 0; i < 16; ++i) pk.h[i] = __float2bfloat16(tile[q * 16 + i][r]);
    __hip_bfloat16* dst = O + (size_t)(n0 + r) * 1536 + k0 + q * 16;
    *(uint4*)dst = pk.u[0];
    *(uint4*)(dst + 8) = pk.u[1];
  }
}

// ---------------- bf16 MFMA GEMM: 32x64 tile, BK=64, XOR-swizzled LDS, XCD remap.
// 1152 blocks per 512x1536 slice (16 m-tiles x 24 n-tiles); 4 waves, wave w owns cols
// w*16..w*16+15 (1 B-frag), both 16-row A-frags shared. If PREPW, tail blocks past 1152:
// [1152,2176) Whh swizzle+cvt, [2176,3040) in_proj cvt, [3040,3328) out_proj cvt (x4 fattened).
// CMODE: 0 = fp32 store, 1 = bf16 store, 2 = fused avg (atomicAdd sum_rows (C+bias)*cat/64)
template <int CMODE, bool BIAS, bool PREPW>
__global__ __launch_bounds__(256) void mfma_gemm(
    const __hip_bfloat16* __restrict__ A, long As,
    const __hip_bfloat16* __restrict__ Bm, long Bs,
    const float* __restrict__ bias, long biasS,
    void* __restrict__ Cp, long Cs,
    const float* __restrict__ catp, float* __restrict__ avgp,
    const float* __restrict__ Whh_f, const float* __restrict__ Whh_b,
    __hip_bfloat16* __restrict__ whh16s,
    const float* __restrict__ ipw, const float* __restrict__ opw,
    __hip_bfloat16* __restrict__ inproj16, __hip_bfloat16* __restrict__ outproj16) {
  constexpr int K = 1536, N = 1536;
  const int bid = blockIdx.x, t = threadIdx.x;
  if (PREPW && bid >= 1152) {
    int tb = bid - 1152;
    if (tb < 1024) {
#pragma unroll
      for (int c = 0; c < 4; ++c) {
        int id = tb * 1024 + c * 256 + t;              // 0..2^20-1
        int lane = id & 63, half = (id >> 6) & 1, row = (id >> 7) & 4095, d = id >> 19;
        const float* W = d ? Whh_b : Whh_f;
        const float* srcp = W + (size_t)row * 1024 + half * 512 + lane;
        union { uint4 u; __hip_bfloat16 h[8]; } pk;
#pragma unroll
        for (int e = 0; e < 8; ++e) pk.h[e] = __float2bfloat16(srcp[e * 64]);
        *(uint4*)(whh16s + (size_t)id * 8) = pk.u;
      }
    } else {
      const float* src; __hip_bfloat16* dst; int base;
      if (tb < 1888) { src = ipw; dst = inproj16; base = (tb - 1024) * 1024; }
      else { src = opw; dst = outproj16; base = (tb - 1888) * 1024; }
#pragma unroll
      for (int c = 0; c < 4; ++c) {
        int i = base + c * 256 + t;
        float4 a = ((const float4*)src)[2 * i], b = ((const float4*)src)[2 * i + 1];
        *(uint4*)(dst + (size_t)i * 8) = pack8(a, b);
      }
    }
    return;
  }
  const int L = bid % 384, z = bid / 384;
  A += (size_t)z * As; Bm += (size_t)z * Bs;
  if (BIAS) bias += (size_t)z * biasS;
  __shared__ __align__(16) short Abuf[32 * 64];   // 4 KB
  __shared__ __align__(16) short Bbuf[64 * 64];   // 8 KB
  // XCD remap: column bxs constant per XCD group (L in [0,384))
  const int bxs = (L & 7) + 8 * ((L >> 3) % 3);
  const int bys = (L >> 3) / 3;                   // 0..15
  const int i0 = bys * 32, j0 = bxs * 64;
  const int lane = t & 63, wave = t >> 6;
  f32x4_t acc[2] = {};

  // A staging: slot t (32 rows x 8 chunks); B staging: slots t, t+256 (64 rows x 8)
  const int rA = t >> 3, qA = t & 7;
  const char* Ag = (const char*)(A + (size_t)(i0 + rA) * K) + qA * 16;
  char* const Asw = (char*)Abuf + ((rA * 128 + qA * 16) ^ ((rA & 7) << 4));
  const int rB0 = t >> 3, qB0 = t & 7;
  const int tb1 = t + 256, rB1 = tb1 >> 3, qB1 = tb1 & 7;
  const char* Bg0 = (const char*)(Bm + (size_t)(j0 + rB0) * K) + qB0 * 16;
  const char* Bg1 = (const char*)(Bm + (size_t)(j0 + rB1) * K) + qB1 * 16;
  char* const Bsw0 = (char*)Bbuf + ((rB0 * 128 + qB0 * 16) ^ ((rB0 & 7) << 4));
  char* const Bsw1 = (char*)Bbuf + ((rB1 * 128 + qB1 * 16) ^ ((rB1 & 7) << 4));

  for (int kb = 0; kb < K * 2; kb += 128) {
    uint4 a0 = *(const uint4*)(Ag + kb);
    uint4 b0 = *(const uint4*)(Bg0 + kb);
    uint4 b1 = *(const uint4*)(Bg1 + kb);
    __syncthreads();
    *(uint4*)Asw = a0;
    *(uint4*)Bsw0 = b0; *(uint4*)Bsw1 = b1;
    __syncthreads();
#pragma unroll
    for (int ks = 0; ks < 2; ++ks) {
      short8_t af[2], bf;
#pragma unroll
      for (int mi = 0; mi < 2; ++mi) {
        int rr = mi * 16 + (lane & 15);
        int off = (rr * 128 + ks * 64 + (lane >> 4) * 16) ^ ((rr & 7) << 4);
        af[mi] = *(const short8_t*)((const char*)Abuf + off);
      }
      {
        int rr = wave * 16 + (lane & 15);
        int off = (rr * 128 + ks * 64 + (lane >> 4) * 16) ^ ((rr & 7) << 4);
        bf = *(const short8_t*)((const char*)Bbuf + off);
      }
#pragma unroll
      for (int mi = 0; mi < 2; ++mi)
        acc[mi] = __builtin_amdgcn_mfma_f32_16x16x32_bf16(af[mi], bf, acc[mi], 0, 0, 0);
    }
  }
  const int col = j0 + wave * 16 + (lane & 15);
  if (CMODE == 2) {
    const int b = bys >> 1;   // 32-row tile -> batch
    float bv = bias[col];
    float p = 0.f;
#pragma unroll
    for (int mi = 0; mi < 2; ++mi) {
      int rbase = i0 + mi * 16 + (lane >> 4) * 4;
#pragma unroll
      for (int r = 0; r < 4; ++r)
        p += (acc[mi][r] + bv) * catp[(size_t)(rbase + r) * 1536 + col];
    }
    p += __shfl_xor(p, 16);
    p += __shfl_xor(p, 32);
    if (lane < 16) atomicAdd(&avgp[(size_t)b * 1536 + col], p * (1.0f / 64.0f));
  } else {
    float bv = BIAS ? bias[col] : 0.f;
#pragma unroll
    for (int mi = 0; mi < 2; ++mi) {
      int r0 = i0 + mi * 16 + (lane >> 4) * 4;
#pragma unroll
      for (int r = 0; r < 4; ++r) {
        float val = acc[mi][r] + bv;
        if (CMODE == 1)
          ((__hip_bfloat16*)Cp)[(size_t)z * Cs + (size_t)(r0 + r) * N + col] = __float2bfloat16(val);
        else
          ((float*)Cp)[(size_t)z * Cs + (size_t)(r0 + r) * N + col] = val;
      }
    }
  }
}

// ---------------- MFMA attention: one block per (b,h); 96 blocks; bf16 in/out.
__global__ __launch_bounds__(256) void attn2_kernel(
    const __hip_bfloat16* __restrict__ qkv, __hip_bfloat16* __restrict__ o) {
  __shared__ __align__(16) ushort Qs[64 * 128];
  __shared__ __align__(16) ushort Ks[64 * 128];
  __shared__ __align__(16) ushort Vt[128 * 72];
  __shared__ __align__(16) ushort Ps[64 * 72];
  __shared__ float redmax[2][64];
  __shared__ float redsum[2][64];
  const int b = blockIdx.x / 12, h = blockIdx.x % 12;
  const int tid = threadIdx.x, lane = tid & 63, wave = tid >> 6;
  const int wr = wave >> 1, wc = wave & 1;
  const size_t base = (size_t)b * 64 * 1536 + (size_t)h * 128;
  const __hip_bfloat16* qg = qkv + base;
  const __hip_bfloat16* kg = qkv + 786432 + base;
  const __hip_bfloat16* vg = qkv + 2 * 786432 + base;

  for (int s = tid; s < 1024; s += 256) {
    int row = s >> 4, q4 = s & 15;
    int q4s = (q4 & 8) | ((q4 & 7) ^ (row & 7));
    uint4 qv = *(const uint4*)(qg + (size_t)row * 1536 + q4 * 8);
    uint4 kv = *(const uint4*)(kg + (size_t)row * 1536 + q4 * 8);
    *(uint4*)&Qs[row * 128 + q4s * 8] = qv;
    *(uint4*)&Ks[row * 128 + q4s * 8] = kv;
    uint4 vv = *(const uint4*)(vg + (size_t)row * 1536 + q4 * 8);
    const ushort* ve = (const ushort*)&vv;
    int colv = (((row >> 3) ^ (q4 & 7)) << 3) | (row & 7);
#pragma unroll
    for (int e = 0; e < 8; ++e) Vt[(q4 * 8 + e) * 72 + colv] = ve[e];
  }
  __syncthreads();

  f32x4_t sacc[2][2] = {};
#pragma unroll
  for (int ks = 0; ks < 4; ++ks) {
    short8_t qf[2], kf[2];
#pragma unroll
    for (int mi = 0; mi < 2; ++mi) {
      int rr = wr * 32 + mi * 16 + (lane & 15);
      int slot = ks * 4 + (lane >> 4);
      int slot2 = (slot & 8) | ((slot & 7) ^ (rr & 7));
      qf[mi] = *(const short8_t*)&Qs[rr * 128 + slot2 * 8];
    }
#pragma unroll
    for (int ni = 0; ni < 2; ++ni) {
      int rr = wc * 32 + ni * 16 + (lane & 15);
      int slot = ks * 4 + (lane >> 4);
      int slot2 = (slot & 8) | ((slot & 7) ^ (rr & 7));
      kf[ni] = *(const short8_t*)&Ks[rr * 128 + slot2 * 8];
    }
#pragma unroll
    for (int mi = 0; mi < 2; ++mi)
#pragma unroll
      for (int ni = 0; ni < 2; ++ni)
        sacc[mi][ni] = __builtin_amdgcn_mfma_f32_16x16x32_bf16(qf[mi], kf[ni], sacc[mi][ni], 0, 0, 0);
  }

  const float scale = 0.08838834764831845f;
  float pv[2][2][4];
#pragma unroll
  for (int mi = 0; mi < 2; ++mi)
#pragma unroll
    for (int r = 0; r < 4; ++r) {
      float a0 = sacc[mi][0][r] * scale, a1 = sacc[mi][1][r] * scale;
      pv[mi][0][r] = a0; pv[mi][1][r] = a1;
      float m0 = fmaxf(a0, a1);
      m0 = fmaxf(m0, __shfl_xor(m0, 1));
      m0 = fmaxf(m0, __shfl_xor(m0, 2));
      m0 = fmaxf(m0, __shfl_xor(m0, 4));
      m0 = fmaxf(m0, __shfl_xor(m0, 8));
      if ((lane & 15) == 0) redmax[wc][wr * 32 + mi * 16 + (lane >> 4) * 4 + r] = m0;
    }
  __syncthreads();
#pragma unroll
  for (int mi = 0; mi < 2; ++mi)
#pragma unroll
    for (int r = 0; r < 4; ++r) {
      int row = wr * 32 + mi * 16 + (lane >> 4) * 4 + r;
      float gm = fmaxf(redmax[0][row], redmax[1][row]);
      float e0 = __expf(pv[mi][0][r] - gm);
      float e1 = __expf(pv[mi][1][r] - gm);
      pv[mi][0][r] = e0; pv[mi][1][r] = e1;
      float s0 = e0 + e1;
      s0 += __shfl_xor(s0, 1);
      s0 += __shfl_xor(s0, 2);
      s0 += __shfl_xor(s0, 4);
      s0 += __shfl_xor(s0, 8);
      if ((lane & 15) == 0) redsum[wc][row] = s0;
      int col0 = wc * 32 + (lane & 15);
      Ps[row * 72 + col0] = __bfloat16_as_ushort(__float2bfloat16(e0));
      Ps[row * 72 + col0 + 16] = __bfloat16_as_ushort(__float2bfloat16(e1));
    }
  __syncthreads();

  f32x4_t oacc[2][4] = {};
#pragma unroll
  for (int ks = 0; ks < 2; ++ks) {
    short8_t pf[2], vf[4];
#pragma unroll
    for (int mi = 0; mi < 2; ++mi) {
      int rr = wr * 32 + mi * 16 + (lane & 15);
      pf[mi] = *(const short8_t*)&Ps[rr * 72 + ks * 32 + (lane >> 4) * 8];
    }
#pragma unroll
    for (int ni = 0; ni < 4; ++ni) {
      int rr = wc * 64 + ni * 16 + (lane & 15);
      int mb = (ks * 4 + (lane >> 4)) ^ ((rr >> 3) & 7);
      vf[ni] = *(const short8_t*)&Vt[rr * 72 + mb * 8];
    }
#pragma unroll
    for (int mi = 0; mi < 2; ++mi)
#pragma unroll
      for (int ni = 0; ni < 4; ++ni)
        oacc[mi][ni] = __builtin_amdgcn_mfma_f32_16x16x32_bf16(pf[mi], vf[ni], oacc[mi][ni], 0, 0, 0);
  }

#pragma unroll
  for (int mi = 0; mi < 2; ++mi)
#pragma unroll
    for (int r = 0; r < 4; ++r) {
      int row = wr * 32 + mi * 16 + (lane >> 4) * 4 + r;
      float inv = 1.f / (redsum[0][row] + redsum[1][row]);
#pragma unroll
      for (int ni = 0; ni < 4; ++ni) {
        int col = wc * 64 + ni * 16 + (lane & 15);
        o[base + (size_t)row * 1536 + col] = __float2bfloat16(oacc[mi][ni][r] * inv);
      }
    }
}

// ---------------- lstm_pre3: 2048 blocks; block bid owns (d = bid>>10, unit u = bid&1023);
// wave w computes gate-row j = w*1024+u for all 8 r. Fuses LSTM step 0 (h=0 -> gates=xg).
__global__ __launch_bounds__(256) void lstm_pre3_kernel(
    const float* __restrict__ avg,
    const float* __restrict__ Wih_f, const float* __restrict__ bih_f, const float* __restrict__ bhh_f,
    const float* __restrict__ Wih_b, const float* __restrict__ bih_b, const float* __restrict__ bhh_b,
    float* __restrict__ xg, float* __restrict__ hstate, float* __restrict__ cstate,
    float* __restrict__ hout) {
  __shared__ float g4[4];
  const int bid = blockIdx.x, tid = threadIdx.x;
  const int wave = tid >> 6, lane = tid & 63;
  const int d = bid >> 10, u = bid & 1023;
  const int j = wave * 1024 + u;
  const float* W = d ? Wih_b : Wih_f;
  const float4* wrow = (const float4*)(W + (size_t)j * 1536);
  float4 w[6];
#pragma unroll
  for (int c = 0; c < 6; ++c) w[c] = wrow[c * 64 + lane];
  float s[8] = {};
#pragma unroll
  for (int r = 0; r < 8; ++r) {
    const float4* av = (const float4*)(avg + (size_t)r * 1536);
#pragma unroll
    for (int c = 0; c < 6; ++c) {
      float4 x = av[c * 64 + lane];
      s[r] += w[c].x * x.x + w[c].y * x.y + w[c].z * x.z + w[c].w * x.w;
    }
  }
#pragma unroll
  for (int r = 0; r < 8; ++r)
#pragma unroll
    for (int off = 32; off; off >>= 1) s[r] += __shfl_xor(s[r], off);
  const int r0 = d ? 7 : 0;
  if (lane == 0) {
    float bias = d ? (bih_b[j] + bhh_b[j]) : (bih_f[j] + bhh_f[j]);
#pragma unroll
    for (int r = 0; r < 8; ++r) xg[((size_t)d * 8 + r) * 4096 + j] = s[r] + bias;
    g4[wave] = s[r0] + bias;
  }
  __syncthreads();
  if (tid == 0) {
    float iv = 1.f / (1.f + __expf(-g4[0]));
    float ov = 1.f / (1.f + __expf(-g4[3]));
    float cn = iv * tanhf(g4[2]);
    float hn = ov * tanhf(cn);
    cstate[(size_t)d * 1024 + u] = cn;
    hstate[(size_t)(2 + d) * 1024 + u] = hn;     // read by step s=1 ((s&1)*2+d)
    hout[((size_t)d * 8 + r0) * 1024 + u] = hn;
  }
}

// ---------------- lstm_step2: 512 blocks; block owns dir d=bid>>8, units u0=(bid&255)*4.
__global__ __launch_bounds__(256) void lstm_step2_kernel(
    const __hip_bfloat16* __restrict__ whh16s, const float* __restrict__ xg,
    float* __restrict__ hstate, float* __restrict__ cstate,
    float* __restrict__ hout, int s) {
  const int bid = blockIdx.x;
  const int d = bid >> 8, u0 = (bid & 255) * 4;
  const int tid = threadIdx.x, wave = tid >> 6, lane = tid & 63;
  const float* hread = hstate + ((size_t)(s & 1) * 2 + d) * 1024;
  float* hwrite = hstate + ((size_t)((s + 1) & 1) * 2 + d) * 1024;
  float* c = cstate + (size_t)d * 1024;
  const int r = d ? (7 - s) : s;

  float hreg[16];
#pragma unroll
  for (int cc = 0; cc < 16; ++cc) hreg[cc] = hread[cc * 64 + lane];

  __shared__ float gsm[4][4];
#pragma unroll
  for (int ui = 0; ui < 4; ++ui) {
    int row = wave * 1024 + u0 + ui;
    const uint4* wp = (const uint4*)whh16s + ((size_t)d * 4096 + row) * 128 + lane;
    uint4 w0 = wp[0];
    uint4 w1 = wp[64];
    float sacc = 0.f;
#pragma unroll
    for (int e4 = 0; e4 < 4; ++e4) {
      uint32_t u = ((const uint32_t*)&w0)[e4];
      sacc += __uint_as_float(u << 16) * hreg[2 * e4] +
              __uint_as_float(u & 0xffff0000u) * hreg[2 * e4 + 1];
    }
#pragma unroll
    for (int e4 = 0; e4 < 4; ++e4) {
      uint32_t u = ((const uint32_t*)&w1)[e4];
      sacc += __uint_as_float(u << 16) * hreg[8 + 2 * e4] +
              __uint_as_float(u & 0xffff0000u) * hreg[8 + 2 * e4 + 1];
    }
#pragma unroll
    for (int off = 32; off; off >>= 1) sacc += __shfl_xor(sacc, off);
    if (lane == 0) gsm[wave][ui] = sacc;
  }
  __syncthreads();
  if (tid < 4) {
    int u = u0 + tid;
    const float* xgr = xg + ((size_t)d * 8 + r) * 4096;
    float gi = gsm[0][tid] + xgr[u];
    float gf = gsm[1][tid] + xgr[1024 + u];
    float gg = gsm[2][tid] + xgr[2048 + u];
    float go = gsm[3][tid] + xgr[3072 + u];
    float iv = 1.f / (1.f + __expf(-gi));
    float fv = 1.f / (1.f + __expf(-gf));
    float ov = 1.f / (1.f + __expf(-go));
    float cold = c[u];
    float cn = fv * cold + iv * tanhf(gg);
    float hn = ov * tanhf(cn);
    c[u] = cn;
    hwrite[u] = hn;
    hout[((size_t)d * 8 + r) * 1024 + u] = hn;
  }
}

// ---------------- logits = lstm_out @ out_w.T + out_b ; softmax over 42 classes
__global__ __launch_bounds__(256) void final_kernel(
    const float* __restrict__ hout, const float* __restrict__ out_w,
    const float* __restrict__ out_b, float* __restrict__ outp) {
  __shared__ float lo[2048];
  __shared__ float logits[64];
  const int s = blockIdx.x, tid = threadIdx.x;
  for (int i = tid; i < 1024; i += 256) {
    lo[i] = hout[(size_t)s * 1024 + i];
    lo[1024 + i] = hout[(size_t)(8 + s) * 1024 + i];
  }
  __syncthreads();
  const int wave = tid >> 6, lane = tid & 63;
  for (int cls = wave; cls < 42; cls += 4) {
    const float4* wr = (const float4*)(out_w + (size_t)cls * 2048);
    const float4* xr = (const float4*)lo;
    float acc = 0.f;
#pragma unroll
    for (int t = 0; t < 8; ++t) {
      int k4 = lane + t * 64;
      float4 w = wr[k4];
      float4 x = xr[k4];
      acc += w.x * x.x + w.y * x.y + w.z * x.z + w.w * x.w;
    }
#pragma unroll
    for (int off = 32; off; off >>= 1) acc += __shfl_xor(acc, off);
    if (lane == 0) logits[cls] = acc + out_b[cls];
  }
  __syncthreads();
  if (tid == 0) {
    float mx = -1e30f;
    for (int c2 = 0; c2 < 42; ++c2) mx = fmaxf(mx, logits[c2]);
    float sum = 0.f;
    for (int c2 = 0; c2 < 42; ++c2) {
      float e = __expf(logits[c2] - mx);
      logits[c2] = e;
      sum += e;
    }
    float inv = 1.f / sum;
    for (int c2 = 0; c2 < 42; ++c2) outp[s * 42 + c2] = logits[c2] * inv;
  }
}

extern "C" void kernel_launch(void* const* d_in, const int* in_sizes, int n_in,
                              void* d_out, int out_size, void* d_ws, size_t ws_size,
                              hipStream_t stream) {
  const float* hidden     = (const float*)d_in[0];
  const int*   inds       = (const int*)d_in[1];
  const float* Wkey       = (const float*)d_in[2];
  const float* Wque       = (const float*)d_in[3];
  const float* Wval       = (const float*)d_in[4];
  const float* in_proj_w  = (const float*)d_in[5];
  const float* in_proj_b  = (const float*)d_in[6];
  const float* out_proj_w = (const float*)d_in[7];
  const float* out_proj_b = (const float*)d_in[8];
  const float* Wih_f      = (const float*)d_in[9];
  const float* Whh_f      = (const float*)d_in[10];
  const float* bih_f      = (const float*)d_in[11];
  const float* bhh_f      = (const float*)d_in[12];
  const float* Wih_b      = (const float*)d_in[13];
  const float* Whh_b      = (const float*)d_in[14];
  const float* bih_b      = (const float*)d_in[15];
  const float* bhh_b      = (const float*)d_in[16];
  const float* out_w      = (const float*)d_in[17];
  const float* out_b      = (const float*)d_in[18];
  float* out = (float*)d_out;

  float* ws = (float*)d_ws;
  float* cat      = ws;                    // 786432
  float* avg      = cat + 786432;          // 12288
  float* xg       = avg + 12288;           // 65536
  float* hstate   = xg + 65536;            // 4096
  float* cstate   = hstate + 4096;         // 2048
  float* hout     = cstate + 2048;         // 16384
  __hip_bfloat16* b16 = (__hip_bfloat16*)(hout + 16384);
  __hip_bfloat16* cat16     = b16;                  // 786432
  __hip_bfloat16* Wt16      = cat16 + 786432;       // 3*1536*1536
  __hip_bfloat16* inproj16  = Wt16 + 7077888;       // 4608*1536
  __hip_bfloat16* outproj16 = inproj16 + 7077888;   // 1536*1536
  __hip_bfloat16* kqv1      = outproj16 + 2359296;  // 3*786432
  __hip_bfloat16* qkv16     = kqv1 + 2359296;       // 3*786432
  __hip_bfloat16* ob16      = qkv16 + 2359296;      // 786432
  __hip_bfloat16* whh16s    = ob16 + 786432;        // 2*4096*1024

  prep_all_kernel<<<2240, 256, 0, stream>>>(hidden, inds, Wkey, Wque, Wval,
                                            cat, cat16, Wt16, avg);

  // stage 1: kqv1[z] = cat @ W_z (bf16 out, B = prepped bf16 Wt16); 1152 GEMM blocks
  //          + tails: Whh [1152,2176), in_proj [2176,3040), out_proj [3040,3328)
  mfma_gemm<1, false, true><<<3328, 256, 0, stream>>>(
      cat16, 0, Wt16, 1536L * 1536, nullptr, 0, kqv1, 786432, nullptr, nullptr,
      Whh_f, Whh_b, whh16s, in_proj_w, out_proj_w, inproj16, outproj16);
  // stage 2: qkv16[z] = kqv1[z] @ in_proj_z^T + b_z (bf16 out, prepped bf16 B)
  mfma_gemm<1, true, false><<<1152, 256, 0, stream>>>(
      kqv1, 786432, inproj16, 1536L * 1536, in_proj_b, 1536, qkv16, 786432,
      nullptr, nullptr, nullptr, nullptr, nullptr, nullptr, nullptr, nullptr, nullptr);

  attn2_kernel<<<96, 256, 0, stream>>>(qkv16, ob16);

  // out_proj fused with avg: avg[b] += sum_n (ob@out_proj^T + b) * cat / 64 (prepped bf16 B)
  mfma_gemm<2, true, false><<<384, 256, 0, stream>>>(
      ob16, 0, outproj16, 0, out_proj_b, 0, nullptr, 0, cat, avg,
      nullptr, nullptr, nullptr, nullptr, nullptr, nullptr, nullptr);

  lstm_pre3_kernel<<<2048, 256, 0, stream>>>(avg, Wih_f, bih_f, bhh_f, Wih_b, bih_b, bhh_b,
                                             xg, hstate, cstate, hout);

  for (int s = 1; s < 8; ++s)
    lstm_step2_kernel<<<512, 256, 0, stream>>>(whh16s, xg, hstate, cstate, hout, s);

  final_kernel<<<8, 256, 0, stream>>>(hout, out_w, out_b, out);
}

// Round 17
// 145.383 us; speedup vs baseline: 1.0256x; 1.0148x over previous
//
#include <hip/hip_runtime.h>
#include <hip/hip_bf16.h>
#include <cstdint>

// B=8 N=64 L=256 H=768 E=1536 NH=12 HD=128 HL=1024 C=42 ; rows = B*N = 512

typedef __attribute__((ext_vector_type(8))) short short8_t;
typedef __attribute__((ext_vector_type(4))) float f32x4_t;

__device__ __forceinline__ uint4 pack8(float4 a, float4 b) {
  union { uint4 u; __hip_bfloat16 h[8]; } pk;
  pk.h[0] = __float2bfloat16(a.x); pk.h[1] = __float2bfloat16(a.y);
  pk.h[2] = __float2bfloat16(a.z); pk.h[3] = __float2bfloat16(a.w);
  pk.h[4] = __float2bfloat16(b.x); pk.h[5] = __float2bfloat16(b.y);
  pk.h[6] = __float2bfloat16(b.z); pk.h[7] = __float2bfloat16(b.w);
  return pk.u;
}

// ---------------- prep_all: [0,512) gather (+avg zero for bid<48),
// [512,2240) transpose+cvt of Wkey/Wque/Wval in 64x64 tiles (24x24x3)
__global__ __launch_bounds__(256) void prep_all_kernel(
    const float* __restrict__ hidden, const int* __restrict__ inds,
    const float* __restrict__ Wkey, const float* __restrict__ Wque, const float* __restrict__ Wval,
    float* __restrict__ cat, __hip_bfloat16* __restrict__ cat16,
    __hip_bfloat16* __restrict__ Wt16, float* __restrict__ avg0) {
  const int bid = blockIdx.x, tid = threadIdx.x;
  if (bid < 512) {
    if (bid < 48) avg0[bid * 256 + tid] = 0.f;
    int bn = bid;
    int i0 = inds[bn * 2 + 0], i1 = inds[bn * 2 + 1];
    const float* r0 = hidden + ((size_t)bn * 256 + i0) * 768;
    const float* r1 = hidden + ((size_t)bn * 256 + i1) * 768;
    float* c = cat + (size_t)bn * 1536;
    __hip_bfloat16* c16 = cat16 + (size_t)bn * 1536;
    for (int i = tid; i < 768; i += 256) {
      float a = r0[i], b = r1[i];
      c[i] = a; c[768 + i] = b;
      c16[i] = __float2bfloat16(a); c16[768 + i] = __float2bfloat16(b);
    }
  } else {
    int b2 = bid - 512;
    int z = b2 / 576, rem = b2 % 576, by = rem / 24, bx = rem % 24;
    const float* W = z == 0 ? Wkey : (z == 1 ? Wque : Wval);
    __hip_bfloat16* O = Wt16 + (size_t)z * 1536 * 1536;
    __shared__ float tile[64][65];   // 16.6 KB
    int n0 = bx * 64, k0 = by * 64;
    int r = tid >> 2, q = tid & 3;
#pragma unroll
    for (int j = 0; j < 4; ++j) {
      float4 v = *(const float4*)(W + (size_t)(k0 + r) * 1536 + n0 + q * 16 + j * 4);
      tile[r][q * 16 + j * 4 + 0] = v.x; tile[r][q * 16 + j * 4 + 1] = v.y;
      tile[r][q * 16 + j * 4 + 2] = v.z; tile[r][q * 16 + j * 4 + 3] = v.w;
    }
    __syncthreads();
    union { uint4 u[2]; __hip_bfloat16 h[16]; } pk;
#pragma unroll
    for (int i = 0; i < 16; ++i) pk.h[i] = __float2bfloat16(tile[q * 16 + i][r]);
    __hip_bfloat16* dst = O + (size_t)(n0 + r) * 1536 + k0 + q * 16;
    *(uint4*)dst = pk.u[0];
    *(uint4*)(dst + 8) = pk.u[1];
  }
}

// ---------------- bf16 MFMA GEMM: 32x64 tile, BK=64, XOR-swizzled LDS, XCD remap.
// 1152 GEMM blocks per 512x1536x3 launch. TAIL: 0=none,
// 1 = in_proj cvt in blocks [1152,2016), 2 = Whh swizzle+cvt in blocks [1152,2176).
// CMODE: 0 = fp32 store, 1 = bf16 store, 2 = fused avg (atomicAdd sum_rows (C+bias)*cat/64)
template <int CMODE, bool BIAS, int TAIL>
__global__ __launch_bounds__(256) void mfma_gemm(
    const __hip_bfloat16* __restrict__ A, long As,
    const __hip_bfloat16* __restrict__ Bm, long Bs,
    const float* __restrict__ bias, long biasS,
    void* __restrict__ Cp, long Cs,
    const float* __restrict__ catp, float* __restrict__ avgp,
    const float* __restrict__ tail_src_f, const float* __restrict__ tail_src_b,
    __hip_bfloat16* __restrict__ tail_dst) {
  constexpr int K = 1536, N = 1536;
  const int bid = blockIdx.x, t = threadIdx.x;
  if (TAIL == 1 && bid >= 1152) {
    int tb = bid - 1152;                               // [0,864): in_proj cvt
#pragma unroll
    for (int c = 0; c < 4; ++c) {
      int i = tb * 1024 + c * 256 + t;                 // < 884736
      float4 a = ((const float4*)tail_src_f)[2 * i], b = ((const float4*)tail_src_f)[2 * i + 1];
      *(uint4*)(tail_dst + (size_t)i * 8) = pack8(a, b);
    }
    return;
  }
  if (TAIL == 2 && bid >= 1152) {
    int tb = bid - 1152;                               // [0,1024): Whh swizzle
#pragma unroll
    for (int c = 0; c < 4; ++c) {
      int id = tb * 1024 + c * 256 + t;                // < 2^20
      int lane = id & 63, half = (id >> 6) & 1, row = (id >> 7) & 4095, d = id >> 19;
      const float* W = d ? tail_src_b : tail_src_f;
      const float* srcp = W + (size_t)row * 1024 + half * 512 + lane;
      union { uint4 u; __hip_bfloat16 h[8]; } pk;
#pragma unroll
      for (int e = 0; e < 8; ++e) pk.h[e] = __float2bfloat16(srcp[e * 64]);
      *(uint4*)(tail_dst + (size_t)id * 8) = pk.u;
    }
    return;
  }
  const int L = bid % 384, z = bid / 384;
  A += (size_t)z * As; Bm += (size_t)z * Bs;
  if (BIAS) bias += (size_t)z * biasS;
  __shared__ __align__(16) short Abuf[32 * 64];   // 4 KB
  __shared__ __align__(16) short Bbuf[64 * 64];   // 8 KB
  const int bxs = (L & 7) + 8 * ((L >> 3) % 3);
  const int bys = (L >> 3) / 3;                   // 0..15
  const int i0 = bys * 32, j0 = bxs * 64;
  const int lane = t & 63, wave = t >> 6;
  f32x4_t acc[2] = {};

  const int rA = t >> 3, qA = t & 7;
  const char* Ag = (const char*)(A + (size_t)(i0 + rA) * K) + qA * 16;
  char* const Asw = (char*)Abuf + ((rA * 128 + qA * 16) ^ ((rA & 7) << 4));
  const int rB0 = t >> 3, qB0 = t & 7;
  const int tb1 = t + 256, rB1 = tb1 >> 3, qB1 = tb1 & 7;
  const char* Bg0 = (const char*)(Bm + (size_t)(j0 + rB0) * K) + qB0 * 16;
  const char* Bg1 = (const char*)(Bm + (size_t)(j0 + rB1) * K) + qB1 * 16;
  char* const Bsw0 = (char*)Bbuf + ((rB0 * 128 + qB0 * 16) ^ ((rB0 & 7) << 4));
  char* const Bsw1 = (char*)Bbuf + ((rB1 * 128 + qB1 * 16) ^ ((rB1 & 7) << 4));

  for (int kb = 0; kb < K * 2; kb += 128) {
    uint4 a0 = *(const uint4*)(Ag + kb);
    uint4 b0 = *(const uint4*)(Bg0 + kb);
    uint4 b1 = *(const uint4*)(Bg1 + kb);
    __syncthreads();
    *(uint4*)Asw = a0;
    *(uint4*)Bsw0 = b0; *(uint4*)Bsw1 = b1;
    __syncthreads();
#pragma unroll
    for (int ks = 0; ks < 2; ++ks) {
      short8_t af[2], bf;
#pragma unroll
      for (int mi = 0; mi < 2; ++mi) {
        int rr = mi * 16 + (lane & 15);
        int off = (rr * 128 + ks * 64 + (lane >> 4) * 16) ^ ((rr & 7) << 4);
        af[mi] = *(const short8_t*)((const char*)Abuf + off);
      }
      {
        int rr = wave * 16 + (lane & 15);
        int off = (rr * 128 + ks * 64 + (lane >> 4) * 16) ^ ((rr & 7) << 4);
        bf = *(const short8_t*)((const char*)Bbuf + off);
      }
#pragma unroll
      for (int mi = 0; mi < 2; ++mi)
        acc[mi] = __builtin_amdgcn_mfma_f32_16x16x32_bf16(af[mi], bf, acc[mi], 0, 0, 0);
    }
  }
  const int col = j0 + wave * 16 + (lane & 15);
  if (CMODE == 2) {
    const int b = bys >> 1;   // 32-row tile -> batch
    float bv = bias[col];
    float p = 0.f;
#pragma unroll
    for (int mi = 0; mi < 2; ++mi) {
      int rbase = i0 + mi * 16 + (lane >> 4) * 4;
#pragma unroll
      for (int r = 0; r < 4; ++r)
        p += (acc[mi][r] + bv) * catp[(size_t)(rbase + r) * 1536 + col];
    }
    p += __shfl_xor(p, 16);
    p += __shfl_xor(p, 32);
    if (lane < 16) atomicAdd(&avgp[(size_t)b * 1536 + col], p * (1.0f / 64.0f));
  } else {
    float bv = BIAS ? bias[col] : 0.f;
#pragma unroll
    for (int mi = 0; mi < 2; ++mi) {
      int r0 = i0 + mi * 16 + (lane >> 4) * 4;
#pragma unroll
      for (int r = 0; r < 4; ++r) {
        float val = acc[mi][r] + bv;
        if (CMODE == 1)
          ((__hip_bfloat16*)Cp)[(size_t)z * Cs + (size_t)(r0 + r) * N + col] = __float2bfloat16(val);
        else
          ((float*)Cp)[(size_t)z * Cs + (size_t)(r0 + r) * N + col] = val;
      }
    }
  }
}

// ---------------- MFMA attention: blocks [0,96) = one (b,h) each; blocks [96,384)
// tail-convert out_proj fp32->bf16 (consumed by gemm3, launched after attn completes).
__global__ __launch_bounds__(256) void attn2_kernel(
    const __hip_bfloat16* __restrict__ qkv, __hip_bfloat16* __restrict__ o,
    const float* __restrict__ opw, __hip_bfloat16* __restrict__ outproj16) {
  __shared__ __align__(16) ushort Qs[64 * 128];
  __shared__ __align__(16) ushort Ks[64 * 128];
  __shared__ __align__(16) ushort Vt[128 * 72];
  __shared__ __align__(16) ushort Ps[64 * 72];
  __shared__ float redmax[2][64];
  __shared__ float redsum[2][64];
  const int tid = threadIdx.x;
  if (blockIdx.x >= 96) {
    int tb = blockIdx.x - 96;                          // [0,288): out_proj cvt
#pragma unroll
    for (int c = 0; c < 4; ++c) {
      int i = tb * 1024 + c * 256 + tid;               // < 294912
      float4 a = ((const float4*)opw)[2 * i], b = ((const float4*)opw)[2 * i + 1];
      *(uint4*)(outproj16 + (size_t)i * 8) = pack8(a, b);
    }
    return;
  }
  const int b = blockIdx.x / 12, h = blockIdx.x % 12;
  const int lane = tid & 63, wave = tid >> 6;
  const int wr = wave >> 1, wc = wave & 1;
  const size_t base = (size_t)b * 64 * 1536 + (size_t)h * 128;
  const __hip_bfloat16* qg = qkv + base;
  const __hip_bfloat16* kg = qkv + 786432 + base;
  const __hip_bfloat16* vg = qkv + 2 * 786432 + base;

  for (int s = tid; s < 1024; s += 256) {
    int row = s >> 4, q4 = s & 15;
    int q4s = (q4 & 8) | ((q4 & 7) ^ (row & 7));
    uint4 qv = *(const uint4*)(qg + (size_t)row * 1536 + q4 * 8);
    uint4 kv = *(const uint4*)(kg + (size_t)row * 1536 + q4 * 8);
    *(uint4*)&Qs[row * 128 + q4s * 8] = qv;
    *(uint4*)&Ks[row * 128 + q4s * 8] = kv;
    uint4 vv = *(const uint4*)(vg + (size_t)row * 1536 + q4 * 8);
    const ushort* ve = (const ushort*)&vv;
    int colv = (((row >> 3) ^ (q4 & 7)) << 3) | (row & 7);
#pragma unroll
    for (int e = 0; e < 8; ++e) Vt[(q4 * 8 + e) * 72 + colv] = ve[e];
  }
  __syncthreads();

  f32x4_t sacc[2][2] = {};
#pragma unroll
  for (int ks = 0; ks < 4; ++ks) {
    short8_t qf[2], kf[2];
#pragma unroll
    for (int mi = 0; mi < 2; ++mi) {
      int rr = wr * 32 + mi * 16 + (lane & 15);
      int slot = ks * 4 + (lane >> 4);
      int slot2 = (slot & 8) | ((slot & 7) ^ (rr & 7));
      qf[mi] = *(const short8_t*)&Qs[rr * 128 + slot2 * 8];
    }
#pragma unroll
    for (int ni = 0; ni < 2; ++ni) {
      int rr = wc * 32 + ni * 16 + (lane & 15);
      int slot = ks * 4 + (lane >> 4);
      int slot2 = (slot & 8) | ((slot & 7) ^ (rr & 7));
      kf[ni] = *(const short8_t*)&Ks[rr * 128 + slot2 * 8];
    }
#pragma unroll
    for (int mi = 0; mi < 2; ++mi)
#pragma unroll
      for (int ni = 0; ni < 2; ++ni)
        sacc[mi][ni] = __builtin_amdgcn_mfma_f32_16x16x32_bf16(qf[mi], kf[ni], sacc[mi][ni], 0, 0, 0);
  }

  const float scale = 0.08838834764831845f;
  float pv[2][2][4];
#pragma unroll
  for (int mi = 0; mi < 2; ++mi)
#pragma unroll
    for (int r = 0; r < 4; ++r) {
      float a0 = sacc[mi][0][r] * scale, a1 = sacc[mi][1][r] * scale;
      pv[mi][0][r] = a0; pv[mi][1][r] = a1;
      float m0 = fmaxf(a0, a1);
      m0 = fmaxf(m0, __shfl_xor(m0, 1));
      m0 = fmaxf(m0, __shfl_xor(m0, 2));
      m0 = fmaxf(m0, __shfl_xor(m0, 4));
      m0 = fmaxf(m0, __shfl_xor(m0, 8));
      if ((lane & 15) == 0) redmax[wc][wr * 32 + mi * 16 + (lane >> 4) * 4 + r] = m0;
    }
  __syncthreads();
#pragma unroll
  for (int mi = 0; mi < 2; ++mi)
#pragma unroll
    for (int r = 0; r < 4; ++r) {
      int row = wr * 32 + mi * 16 + (lane >> 4) * 4 + r;
      float gm = fmaxf(redmax[0][row], redmax[1][row]);
      float e0 = __expf(pv[mi][0][r] - gm);
      float e1 = __expf(pv[mi][1][r] - gm);
      pv[mi][0][r] = e0; pv[mi][1][r] = e1;
      float s0 = e0 + e1;
      s0 += __shfl_xor(s0, 1);
      s0 += __shfl_xor(s0, 2);
      s0 += __shfl_xor(s0, 4);
      s0 += __shfl_xor(s0, 8);
      if ((lane & 15) == 0) redsum[wc][row] = s0;
      int col0 = wc * 32 + (lane & 15);
      Ps[row * 72 + col0] = __bfloat16_as_ushort(__float2bfloat16(e0));
      Ps[row * 72 + col0 + 16] = __bfloat16_as_ushort(__float2bfloat16(e1));
    }
  __syncthreads();

  f32x4_t oacc[2][4] = {};
#pragma unroll
  for (int ks = 0; ks < 2; ++ks) {
    short8_t pf[2], vf[4];
#pragma unroll
    for (int mi = 0; mi < 2; ++mi) {
      int rr = wr * 32 + mi * 16 + (lane & 15);
      pf[mi] = *(const short8_t*)&Ps[rr * 72 + ks * 32 + (lane >> 4) * 8];
    }
#pragma unroll
    for (int ni = 0; ni < 4; ++ni) {
      int rr = wc * 64 + ni * 16 + (lane & 15);
      int mb = (ks * 4 + (lane >> 4)) ^ ((rr >> 3) & 7);
      vf[ni] = *(const short8_t*)&Vt[rr * 72 + mb * 8];
    }
#pragma unroll
    for (int mi = 0; mi < 2; ++mi)
#pragma unroll
      for (int ni = 0; ni < 4; ++ni)
        oacc[mi][ni] = __builtin_amdgcn_mfma_f32_16x16x32_bf16(pf[mi], vf[ni], oacc[mi][ni], 0, 0, 0);
  }

#pragma unroll
  for (int mi = 0; mi < 2; ++mi)
#pragma unroll
    for (int r = 0; r < 4; ++r) {
      int row = wr * 32 + mi * 16 + (lane >> 4) * 4 + r;
      float inv = 1.f / (redsum[0][row] + redsum[1][row]);
#pragma unroll
      for (int ni = 0; ni < 4; ++ni) {
        int col = wc * 64 + ni * 16 + (lane & 15);
        o[base + (size_t)row * 1536 + col] = __float2bfloat16(oacc[mi][ni][r] * inv);
      }
    }
}

// ---------------- lstm_pre3: 2048 blocks; block bid owns (d = bid>>10, unit u = bid&1023);
// wave w computes gate-row j = w*1024+u for all 8 r. Fuses LSTM step 0 (h=0 -> gates=xg).
__global__ __launch_bounds__(256) void lstm_pre3_kernel(
    const float* __restrict__ avg,
    const float* __restrict__ Wih_f, const float* __restrict__ bih_f, const float* __restrict__ bhh_f,
    const float* __restrict__ Wih_b, const float* __restrict__ bih_b, const float* __restrict__ bhh_b,
    float* __restrict__ xg, float* __restrict__ hstate, float* __restrict__ cstate,
    float* __restrict__ hout) {
  __shared__ float g4[4];
  const int bid = blockIdx.x, tid = threadIdx.x;
  const int wave = tid >> 6, lane = tid & 63;
  const int d = bid >> 10, u = bid & 1023;
  const int j = wave * 1024 + u;
  const float* W = d ? Wih_b : Wih_f;
  const float4* wrow = (const float4*)(W + (size_t)j * 1536);
  float4 w[6];
#pragma unroll
  for (int c = 0; c < 6; ++c) w[c] = wrow[c * 64 + lane];
  float s[8] = {};
#pragma unroll
  for (int r = 0; r < 8; ++r) {
    const float4* av = (const float4*)(avg + (size_t)r * 1536);
#pragma unroll
    for (int c = 0; c < 6; ++c) {
      float4 x = av[c * 64 + lane];
      s[r] += w[c].x * x.x + w[c].y * x.y + w[c].z * x.z + w[c].w * x.w;
    }
  }
#pragma unroll
  for (int r = 0; r < 8; ++r)
#pragma unroll
    for (int off = 32; off; off >>= 1) s[r] += __shfl_xor(s[r], off);
  const int r0 = d ? 7 : 0;
  if (lane == 0) {
    float bias = d ? (bih_b[j] + bhh_b[j]) : (bih_f[j] + bhh_f[j]);
#pragma unroll
    for (int r = 0; r < 8; ++r) xg[((size_t)d * 8 + r) * 4096 + j] = s[r] + bias;
    g4[wave] = s[r0] + bias;
  }
  __syncthreads();
  if (tid == 0) {
    float iv = 1.f / (1.f + __expf(-g4[0]));
    float ov = 1.f / (1.f + __expf(-g4[3]));
    float cn = iv * tanhf(g4[2]);
    float hn = ov * tanhf(cn);
    cstate[(size_t)d * 1024 + u] = cn;
    hstate[(size_t)(2 + d) * 1024 + u] = hn;     // read by step s=1 ((s&1)*2+d)
    hout[((size_t)d * 8 + r0) * 1024 + u] = hn;
  }
}

// ---------------- lstm_step2: 512 blocks; block owns dir d=bid>>8, units u0=(bid&255)*4.
__global__ __launch_bounds__(256) void lstm_step2_kernel(
    const __hip_bfloat16* __restrict__ whh16s, const float* __restrict__ xg,
    float* __restrict__ hstate, float* __restrict__ cstate,
    float* __restrict__ hout, int s) {
  const int bid = blockIdx.x;
  const int d = bid >> 8, u0 = (bid & 255) * 4;
  const int tid = threadIdx.x, wave = tid >> 6, lane = tid & 63;
  const float* hread = hstate + ((size_t)(s & 1) * 2 + d) * 1024;
  float* hwrite = hstate + ((size_t)((s + 1) & 1) * 2 + d) * 1024;
  float* c = cstate + (size_t)d * 1024;
  const int r = d ? (7 - s) : s;

  float hreg[16];
#pragma unroll
  for (int cc = 0; cc < 16; ++cc) hreg[cc] = hread[cc * 64 + lane];

  __shared__ float gsm[4][4];
#pragma unroll
  for (int ui = 0; ui < 4; ++ui) {
    int row = wave * 1024 + u0 + ui;
    const uint4* wp = (const uint4*)whh16s + ((size_t)d * 4096 + row) * 128 + lane;
    uint4 w0 = wp[0];
    uint4 w1 = wp[64];
    float sacc = 0.f;
#pragma unroll
    for (int e4 = 0; e4 < 4; ++e4) {
      uint32_t u = ((const uint32_t*)&w0)[e4];
      sacc += __uint_as_float(u << 16) * hreg[2 * e4] +
              __uint_as_float(u & 0xffff0000u) * hreg[2 * e4 + 1];
    }
#pragma unroll
    for (int e4 = 0; e4 < 4; ++e4) {
      uint32_t u = ((const uint32_t*)&w1)[e4];
      sacc += __uint_as_float(u << 16) * hreg[8 + 2 * e4] +
              __uint_as_float(u & 0xffff0000u) * hreg[8 + 2 * e4 + 1];
    }
#pragma unroll
    for (int off = 32; off; off >>= 1) sacc += __shfl_xor(sacc, off);
    if (lane == 0) gsm[wave][ui] = sacc;
  }
  __syncthreads();
  if (tid < 4) {
    int u = u0 + tid;
    const float* xgr = xg + ((size_t)d * 8 + r) * 4096;
    float gi = gsm[0][tid] + xgr[u];
    float gf = gsm[1][tid] + xgr[1024 + u];
    float gg = gsm[2][tid] + xgr[2048 + u];
    float go = gsm[3][tid] + xgr[3072 + u];
    float iv = 1.f / (1.f + __expf(-gi));
    float fv = 1.f / (1.f + __expf(-gf));
    float ov = 1.f / (1.f + __expf(-go));
    float cold = c[u];
    float cn = fv * cold + iv * tanhf(gg);
    float hn = ov * tanhf(cn);
    c[u] = cn;
    hwrite[u] = hn;
    hout[((size_t)d * 8 + r) * 1024 + u] = hn;
  }
}

// ---------------- logits = lstm_out @ out_w.T + out_b ; softmax over 42 classes
__global__ __launch_bounds__(256) void final_kernel(
    const float* __restrict__ hout, const float* __restrict__ out_w,
    const float* __restrict__ out_b, float* __restrict__ outp) {
  __shared__ float lo[2048];
  __shared__ float logits[64];
  const int s = blockIdx.x, tid = threadIdx.x;
  for (int i = tid; i < 1024; i += 256) {
    lo[i] = hout[(size_t)s * 1024 + i];
    lo[1024 + i] = hout[(size_t)(8 + s) * 1024 + i];
  }
  __syncthreads();
  const int wave = tid >> 6, lane = tid & 63;
  for (int cls = wave; cls < 42; cls += 4) {
    const float4* wr = (const float4*)(out_w + (size_t)cls * 2048);
    const float4* xr = (const float4*)lo;
    float acc = 0.f;
#pragma unroll
    for (int t = 0; t < 8; ++t) {
      int k4 = lane + t * 64;
      float4 w = wr[k4];
      float4 x = xr[k4];
      acc += w.x * x.x + w.y * x.y + w.z * x.z + w.w * x.w;
    }
#pragma unroll
    for (int off = 32; off; off >>= 1) acc += __shfl_xor(acc, off);
    if (lane == 0) logits[cls] = acc + out_b[cls];
  }
  __syncthreads();
  if (tid == 0) {
    float mx = -1e30f;
    for (int c2 = 0; c2 < 42; ++c2) mx = fmaxf(mx, logits[c2]);
    float sum = 0.f;
    for (int c2 = 0; c2 < 42; ++c2) {
      float e = __expf(logits[c2] - mx);
      logits[c2] = e;
      sum += e;
    }
    float inv = 1.f / sum;
    for (int c2 = 0; c2 < 42; ++c2) outp[s * 42 + c2] = logits[c2] * inv;
  }
}

extern "C" void kernel_launch(void* const* d_in, const int* in_sizes, int n_in,
                              void* d_out, int out_size, void* d_ws, size_t ws_size,
                              hipStream_t stream) {
  const float* hidden     = (const float*)d_in[0];
  const int*   inds       = (const int*)d_in[1];
  const float* Wkey       = (const float*)d_in[2];
  const float* Wque       = (const float*)d_in[3];
  const float* Wval       = (const float*)d_in[4];
  const float* in_proj_w  = (const float*)d_in[5];
  const float* in_proj_b  = (const float*)d_in[6];
  const float* out_proj_w = (const float*)d_in[7];
  const float* out_proj_b = (const float*)d_in[8];
  const float* Wih_f      = (const float*)d_in[9];
  const float* Whh_f      = (const float*)d_in[10];
  const float* bih_f      = (const float*)d_in[11];
  const float* bhh_f      = (const float*)d_in[12];
  const float* Wih_b      = (const float*)d_in[13];
  const float* Whh_b      = (const float*)d_in[14];
  const float* bih_b      = (const float*)d_in[15];
  const float* bhh_b      = (const float*)d_in[16];
  const float* out_w      = (const float*)d_in[17];
  const float* out_b      = (const float*)d_in[18];
  float* out = (float*)d_out;

  float* ws = (float*)d_ws;
  float* cat      = ws;                    // 786432
  float* avg      = cat + 786432;          // 12288
  float* xg       = avg + 12288;           // 65536
  float* hstate   = xg + 65536;            // 4096
  float* cstate   = hstate + 4096;         // 2048
  float* hout     = cstate + 2048;         // 16384
  __hip_bfloat16* b16 = (__hip_bfloat16*)(hout + 16384);
  __hip_bfloat16* cat16     = b16;                  // 786432
  __hip_bfloat16* Wt16      = cat16 + 786432;       // 3*1536*1536
  __hip_bfloat16* inproj16  = Wt16 + 7077888;       // 4608*1536
  __hip_bfloat16* outproj16 = inproj16 + 7077888;   // 1536*1536
  __hip_bfloat16* kqv1      = outproj16 + 2359296;  // 3*786432
  __hip_bfloat16* qkv16     = kqv1 + 2359296;       // 3*786432
  __hip_bfloat16* ob16      = qkv16 + 2359296;      // 786432
  __hip_bfloat16* whh16s    = ob16 + 786432;        // 2*4096*1024

  prep_all_kernel<<<2240, 256, 0, stream>>>(hidden, inds, Wkey, Wque, Wval,
                                            cat, cat16, Wt16, avg);

  // stage 1: kqv1[z] = cat @ W_z (bf16 out) + tail: in_proj cvt [1152,2016)
  mfma_gemm<1, false, 1><<<2016, 256, 0, stream>>>(
      cat16, 0, Wt16, 1536L * 1536, nullptr, 0, kqv1, 786432, nullptr, nullptr,
      in_proj_w, nullptr, inproj16);
  // stage 2: qkv16[z] = kqv1[z] @ in_proj_z^T + b_z + tail: Whh swizzle [1152,2176)
  mfma_gemm<1, true, 2><<<2176, 256, 0, stream>>>(
      kqv1, 786432, inproj16, 1536L * 1536, in_proj_b, 1536, qkv16, 786432,
      nullptr, nullptr, Whh_f, Whh_b, whh16s);

  // attn + tail: out_proj cvt [96,384)
  attn2_kernel<<<384, 256, 0, stream>>>(qkv16, ob16, out_proj_w, outproj16);

  // out_proj fused with avg (prepped bf16 B)
  mfma_gemm<2, true, 0><<<384, 256, 0, stream>>>(
      ob16, 0, outproj16, 0, out_proj_b, 0, nullptr, 0, cat, avg,
      nullptr, nullptr, nullptr);

  lstm_pre3_kernel<<<2048, 256, 0, stream>>>(avg, Wih_f, bih_f, bhh_f, Wih_b, bih_b, bhh_b,
                                             xg, hstate, cstate, hout);

  for (int s = 1; s < 8; ++s)
    lstm_step2_kernel<<<512, 256, 0, stream>>>(whh16s, xg, hstate, cstate, hout, s);

  final_kernel<<<8, 256, 0, stream>>>(hout, out_w, out_b, out);
}